// Round 8
// baseline (3660.987 us; speedup 1.0000x reference)
//
#include <hip/hip_runtime.h>
#include <cmath>

typedef _Float16 half8  __attribute__((ext_vector_type(8)));
typedef _Float16 half4v __attribute__((ext_vector_type(4)));
typedef float    float4v __attribute__((ext_vector_type(4)));

// ---------------------------------------------------------------------------
// MFMA conv3x3 (SAME), fp16 in / fp32 acc / fp16 out (relu).
// WG = 4 waves; wave tile = (MT*16) co x 144 px. Runtime dims (R6 lesson:
// templating CI unrolls ci-loop, VGPR 108->128, +23% — keep runtime).
// launch_bounds (256,2): (256,4) spilled accs (R3, 14x regression).
// XCD swizzle (R5): id = xcd + 8*(group*NC + co_t) -> all co-tiles of one
// px-block on one XCD; its activation slab stays in that XCD's L2.
// R8: double-buffered weight staging via global_load_lds(16B): prefetch
// stage s+1 into sW[buf^1] right after the stage-s barrier; in-order vmcnt
// retirement hides staging behind the first tap's B-load wait. One barrier
// per stage (was two + serial VGPR->LDS staging).
// MODE 0: att patch read directly from padded image; per-lane edge masks
//         emulate per-patch SAME zero padding (no P1 copy).
// MODE 1: patch buffer [NB][26][26][CI] (ring zeroed).
// MODE 2: image [b][RSin][RSin][CI], 64 tiles/batch, img = px_b (or px_b-NBa).
// MODE 3: merged — px_b < NBa -> MODE0 (att: Wg/bias/out), else MODE2
//         (reg: Wg2/bias2/out2, RSout2).
// ---------------------------------------------------------------------------
template<int MT>
__global__ __launch_bounds__(256, 2)
void mfma_conv(const _Float16* __restrict__ in, const _Float16* __restrict__ Wg,
               const float* __restrict__ bias, _Float16* __restrict__ out,
               const _Float16* __restrict__ Wg2, const float* __restrict__ bias2,
               _Float16* __restrict__ out2,
               int CI, int CO, int RSin, int RSout, int RSout2,
               int MODE, int NB, int NC, int p0, int NBa)
{
    constexpr int SWH = 9 * MT * 64 * 8;               // halves per LDS buffer
    __shared__ __align__(16) _Float16 sW[2 * SWH];

    const int tid  = threadIdx.x;
    const int wave = tid >> 6;
    const int lane = tid & 63;
    const int ll   = lane & 15;
    const int quad = lane >> 4;

    const int id   = blockIdx.x;
    const int xcd  = id & 7;
    const int slot = id >> 3;
    const int px_b = (slot / NC) * 8 + xcd;
    const int co_t = slot % NC;
    if (px_b >= NB) return;
    const int co0 = co_t * (MT * 16);

    int mode = MODE;
    const _Float16* W = Wg;
    const float* bptr = bias;
    _Float16* optr = out;
    int rso = RSout;
    int img_idx = px_b;
    if (MODE == 3) {
        if (px_b < NBa) mode = 0;
        else { mode = 2; img_idx = px_b - NBa; W = Wg2; bptr = bias2; optr = out2; rso = RSout2; }
    }

    size_t in_base, out_base;
    int b_off[9], edge[9];
    int TY = 0, TX = 0;
    if (mode == 0) {
        int pat = p0 + px_b;
        int bb = pat / 225, rem = pat % 225;
        int pi = rem / 15, pj = rem % 15;
        in_base  = (size_t)bb * RSin * RSin * CI;
        out_base = (size_t)px_b * 676 * CO;
        #pragma unroll
        for (int nt = 0; nt < 9; ++nt) {
            int p = wave * 144 + nt * 16 + ll;
            int py = p / 24, px = p % 24;
            b_off[nt] = ((pi * 12 + py) * RSin + (pj * 12 + px)) * CI;
            edge[nt] = (py == 0 ? 1 : 0) | (py == 23 ? 2 : 0)
                     | (px == 0 ? 4 : 0) | (px == 23 ? 8 : 0);
        }
    } else if (mode == 1) {
        in_base  = (size_t)px_b * 676 * CI;
        out_base = (size_t)px_b * 676 * CO;
        #pragma unroll
        for (int nt = 0; nt < 9; ++nt) {
            int p = wave * 144 + nt * 16 + ll;
            b_off[nt] = ((p / 24) * RSin + (p % 24)) * CI;
            edge[nt] = 0;
        }
    } else {
        int bb = img_idx >> 6, tile = img_idx & 63;
        TY = (tile >> 3) * 24; TX = (tile & 7) * 24;
        in_base  = (size_t)bb * RSin * RSin * CI;
        out_base = (size_t)bb * rso * rso * CO;
        #pragma unroll
        for (int nt = 0; nt < 9; ++nt) {
            int p = wave * 144 + nt * 16 + ll;
            b_off[nt] = ((TY + p / 24) * RSin + (TX + p % 24)) * CI;
            edge[nt] = 0;
        }
    }

    // async weight staging: slot c -> LDS base + c*16B; per-wave contiguous
    // (lds dest = wave-uniform base + lane*16, matching global_load_lds DMA).
    auto stage = [&](int ci0, int bsel) {
        _Float16* dst = &sW[bsel * SWH];
        for (int c = tid; c < 9 * MT * 64; c += 256) {
            int lane_s = c & 63;
            int mtt = c >> 6;
            int mt = mtt % MT, t = mtt / MT;
            const _Float16* g = &W[((size_t)(co0 + mt * 16 + (lane_s & 15)) * 9 + t) * CI
                                   + ci0 + (lane_s >> 4) * 8];
            __builtin_amdgcn_global_load_lds(
                (const __attribute__((address_space(1))) void*)g,
                (__attribute__((address_space(3))) void*)(dst + (size_t)c * 8),
                16, 0, 0);
        }
    };

    float4v acc[MT][9];
    #pragma unroll
    for (int mt = 0; mt < MT; ++mt)
        #pragma unroll
        for (int nt = 0; nt < 9; ++nt)
            acc[mt][nt] = (float4v){0.f, 0.f, 0.f, 0.f};

    const int nst = CI >> 5;
    stage(0, 0);
    int bsel = 0;
    for (int s = 0; s < nst; ++s) {
        asm volatile("s_waitcnt vmcnt(0)" ::: "memory");
        __syncthreads();
        if (s + 1 < nst) stage((s + 1) << 5, bsel ^ 1);

        const _Float16* inp = in + in_base + (s << 5) + quad * 8;
        const _Float16* sb = &sW[bsel * SWH];
        #pragma unroll
        for (int dy = 0; dy < 3; ++dy) {
            #pragma unroll
            for (int dx = 0; dx < 3; ++dx) {
                const int t = dy * 3 + dx;
                const int toff = (dy * RSin + dx) * CI;
                const int emask = (dy == 0 ? 1 : 0) | (dy == 2 ? 2 : 0)
                                | (dx == 0 ? 4 : 0) | (dx == 2 ? 8 : 0);
                half8 a[MT];
                #pragma unroll
                for (int mt = 0; mt < MT; ++mt)
                    a[mt] = *(const half8*)&sb[((t * MT + mt) * 64 + lane) * 8];
                #pragma unroll
                for (int nt = 0; nt < 9; ++nt) {
                    uint4 raw = *(const uint4*)(inp + b_off[nt] + toff);
                    bool z = (edge[nt] & emask) != 0;
                    raw.x = z ? 0u : raw.x;
                    raw.y = z ? 0u : raw.y;
                    raw.z = z ? 0u : raw.z;
                    raw.w = z ? 0u : raw.w;
                    half8 b = *(half8*)&raw;
                    #pragma unroll
                    for (int mt = 0; mt < MT; ++mt)
                        acc[mt][nt] = __builtin_amdgcn_mfma_f32_16x16x32_f16(
                            a[mt], b, acc[mt][nt], 0, 0, 0);
                }
            }
        }
        bsel ^= 1;
    }

    // epilogue: bias + relu -> fp16; D layout col=lane&15 (px), row=quad*4+reg
    #pragma unroll
    for (int mt = 0; mt < MT; ++mt) {
        float4v bs = *(const float4v*)&bptr[co0 + mt * 16 + quad * 4];
        #pragma unroll
        for (int nt = 0; nt < 9; ++nt) {
            int p = wave * 144 + nt * 16 + ll;
            int oy = TY + p / 24 + 1, ox = TX + p % 24 + 1;
            size_t ooff = out_base + (size_t)(oy * rso + ox) * CO + co0 + mt * 16 + quad * 4;
            float4v v = acc[mt][nt];
            half4v h;
            h.x = (_Float16)fmaxf(v.x + bs.x, 0.f);
            h.y = (_Float16)fmaxf(v.y + bs.y, 0.f);
            h.z = (_Float16)fmaxf(v.z + bs.z, 0.f);
            h.w = (_Float16)fmaxf(v.w + bs.w, 0.f);
            *(half4v*)(optr + ooff) = h;
        }
    }
}

static inline int swiz_grid(int NB, int NC) { return ((NB + 7) & ~7) * NC; }

// ---------------------------------------------------------------------------
// M=1 conv3 via MFMA, CO padded to 16 (rows 1..15 zero). Runtime CI/RSI.
// MODE 1: patch buffer [NB][26][26][CI]; ACT 1: sigmoid -> outp[blk*576+p]
// MODE 2: image [b][RSI][RSI][CI];       ACT 2: tanh    -> outp[b*36864+...]
// ---------------------------------------------------------------------------
template<int MODE, int ACT>
__global__ __launch_bounds__(256, 2)
void mfma_score(const _Float16* __restrict__ in, const _Float16* __restrict__ W16,
                const float* __restrict__ bias, float* __restrict__ outp,
                int CI, int RSI, int NB)
{
    __shared__ __align__(16) _Float16 sW[9 * 16 * 32];

    const int tid  = threadIdx.x;
    const int wave = tid >> 6;
    const int lane = tid & 63;
    const int ll   = lane & 15;
    const int quad = lane >> 4;

    const int blk = blockIdx.x;
    if (blk >= NB) return;

    size_t in_base;
    int ty = 0, tx = 0, bb = 0;
    if (MODE == 2) {
        bb = blk >> 6; int tile = blk & 63; ty = tile >> 3; tx = tile & 7;
        in_base = (size_t)bb * RSI * RSI * CI;
    } else {
        in_base = (size_t)blk * 676 * CI;
    }

    int b_off[9];
    #pragma unroll
    for (int nt = 0; nt < 9; ++nt) {
        int p = wave * 144 + nt * 16 + ll;
        int py = p / 24, px = p % 24;
        b_off[nt] = (MODE == 2) ? ((ty * 24 + py) * RSI + (tx * 24 + px)) * CI
                                : (py * RSI + px) * CI;
    }

    float4v acc[9];
    #pragma unroll
    for (int nt = 0; nt < 9; ++nt) acc[nt] = (float4v){0.f, 0.f, 0.f, 0.f};

    for (int ci0 = 0; ci0 < CI; ci0 += 32) {
        __syncthreads();
        for (int c = tid; c < 9 * 16 * 4; c += 256) {
            int q = c & 3, tco = c >> 2;
            int t = tco >> 4, co = tco & 15;
            *(uint4*)&sW[tco * 32 + q * 8] =
                *(const uint4*)&W16[((size_t)co * 9 + t) * CI + ci0 + q * 8];
        }
        __syncthreads();

        const _Float16* inp = in + in_base + ci0 + quad * 8;
        for (int dy = 0; dy < 3; ++dy)
            for (int dx = 0; dx < 3; ++dx) {
                const int t = dy * 3 + dx;
                const int toff = (dy * RSI + dx) * CI;
                half8 a = *(const half8*)&sW[(t * 16 + ll) * 32 + quad * 8];
                #pragma unroll
                for (int nt = 0; nt < 9; ++nt) {
                    half8 b = *(const half8*)(inp + b_off[nt] + toff);
                    acc[nt] = __builtin_amdgcn_mfma_f32_16x16x32_f16(a, b, acc[nt], 0, 0, 0);
                }
            }
    }

    if (quad == 0) {
        float bv = bias[0];
        #pragma unroll
        for (int nt = 0; nt < 9; ++nt) {
            int p = wave * 144 + nt * 16 + ll;
            float v = acc[nt].x + bv;
            if (ACT == 1) {
                outp[(size_t)blk * 576 + p] = 1.f / (1.f + expf(-v));
            } else {
                int y = ty * 24 + p / 24, x = tx * 24 + p % 24;
                outp[(size_t)bb * 36864 + y * 192 + x] = tanhf(v);
            }
        }
    }
}

// ---------------------------------------------------------------------------
// helpers
// ---------------------------------------------------------------------------
__global__ __launch_bounds__(256)
void build_x16i(const float* __restrict__ src, const float* __restrict__ tgt,
                _Float16* __restrict__ X)
{
    int idx = blockIdx.x * 256 + threadIdx.x;
    int q = idx & 15, pid = idx >> 4;
    if (pid >= 2 * 36864) return;
    int b = pid / 36864, r = pid % 36864;
    int y = r / 192, x = r % 192;
    half8 h;
    #pragma unroll
    for (int j = 0; j < 8; ++j) {
        int ch = q * 8 + j;
        const float* im = (ch < 64) ? src : tgt;
        h[j] = (_Float16)im[(size_t)(b * 64 + (ch & 63)) * 36864 + r];
    }
    *(half8*)&X[(((size_t)b * 194 + y + 1) * 194 + (x + 1)) * 128 + q * 8] = h;
}

__global__ __launch_bounds__(256)
void cvt_w(const float* __restrict__ src, _Float16* __restrict__ dst, int CO, int CI)
{
    int idx = blockIdx.x * 256 + threadIdx.x;
    if (idx >= CO * 9 * CI) return;
    int ci = idx % CI, t = (idx / CI) % 9, co = idx / (9 * CI);
    dst[idx] = (_Float16)src[((size_t)co * CI + ci) * 9 + t];
}

__global__ __launch_bounds__(256)
void cvt_pad16(const float* __restrict__ src, _Float16* __restrict__ dst, int CI)
{
    int idx = blockIdx.x * 256 + threadIdx.x;
    if (idx >= 16 * 9 * CI) return;
    int ci = idx % CI, t = (idx / CI) % 9, co = idx / (9 * CI);
    dst[idx] = (co == 0) ? (_Float16)src[(size_t)ci * 9 + t] : (_Float16)0.0f;
}

__global__ __launch_bounds__(256)
void ring_zero(_Float16* __restrict__ buf, int npatch, int RS, int CI)
{
    int c8 = CI >> 3;
    int RC = 2 * RS + 2 * (RS - 2);
    int idx = blockIdx.x * 256 + threadIdx.x;
    if (idx >= npatch * RC * c8) return;
    int q = idx % c8, rp = (idx / c8) % RC, pl = idx / (c8 * RC);
    int r, c;
    if (rp < RS)            { r = 0;      c = rp; }
    else if (rp < 2 * RS)   { r = RS - 1; c = rp - RS; }
    else {
        int s = rp - 2 * RS, half = RS - 2;
        if (s < half) { r = s + 1;        c = 0; }
        else          { r = s - half + 1; c = RS - 1; }
    }
    uint4 z = {0u, 0u, 0u, 0u};
    *(uint4*)&buf[((size_t)pl * RS * RS + r * RS + c) * CI + q * 8] = z;
}

__global__ __launch_bounds__(256)
void att_finalize(const float* __restrict__ score, float* __restrict__ out)
{
    int idx = blockIdx.x * 256 + threadIdx.x;
    if (idx >= 2 * 36864) return;
    int b = idx / 36864, r = idx % 36864;
    int y = r / 192, x = r % 192;
    int i_lo = (y >= 24) ? (y - 12) / 12 : 0;
    int i_hi = min(14, y / 12);
    int j_lo = (x >= 24) ? (x - 12) / 12 : 0;
    int j_hi = min(14, x / 12);
    float s = 0.f; int cnt = 0;
    for (int i = i_lo; i <= i_hi; ++i)
        for (int j = j_lo; j <= j_hi; ++j) {
            s += score[(((size_t)b * 15 + i) * 15 + j) * 576 + (y - 12 * i) * 24 + (x - 12 * j)];
            ++cnt;
        }
    out[idx] = s / (float)cnt;
}

// ---------------------------------------------------------------------------
extern "C" void kernel_launch(void* const* d_in, const int* in_sizes, int n_in,
                              void* d_out, int out_size, void* d_ws, size_t ws_size,
                              hipStream_t stream)
{
    const float* src = (const float*)d_in[0];
    const float* tgt = (const float*)d_in[1];
    const float* W1  = (const float*)d_in[2];  const float* b1  = (const float*)d_in[3];
    const float* W2  = (const float*)d_in[4];  const float* b2  = (const float*)d_in[5];
    const float* W3  = (const float*)d_in[6];  const float* b3  = (const float*)d_in[7];
    const float* Wr1 = (const float*)d_in[8];  const float* br1 = (const float*)d_in[9];
    const float* Wr2 = (const float*)d_in[10]; const float* br2 = (const float*)d_in[11];
    const float* Wr3 = (const float*)d_in[12]; const float* br3 = (const float*)d_in[13];
    float* out = (float*)d_out;

    // ---- fixed workspace (halves) ----
    _Float16* ws = (_Float16*)d_ws;
    size_t o = 0;
    _Float16* X16i = ws + o; o += (size_t)2 * 194 * 194 * 128;
    _Float16* W1h  = ws + o; o += (size_t)512 * 9 * 128;
    _Float16* W2h  = ws + o; o += (size_t)256 * 9 * 512;
    _Float16* Wr1h = ws + o; o += (size_t)512 * 9 * 128;
    _Float16* Wr2h = ws + o; o += (size_t)64 * 9 * 512;
    _Float16* W3p  = ws + o; o += (size_t)16 * 9 * 256;
    _Float16* Wr3p = ws + o; o += (size_t)16 * 9 * 64;
    float*    score = (float*)(ws + o); o += 2 * 259200;
    const size_t fixed_h = o;

    // ---- adaptive chunking (no P1 buffer: MODE0 reads the image directly) ----
    const size_t per_patch_h = (size_t)676 * (512 + 256);            // 519,168
    const size_t regA_h = (size_t)2 * 194 * 194 * 512;
    const size_t regB_h = (size_t)2 * 194 * 194 * 64;
    size_t h_avail = ws_size / 2;
    int P = 50;
    {
        size_t n450 = 450 * per_patch_h + regA_h + regB_h;           // separate reg bufs
        size_t n150 = 150 * per_patch_h;                             // reg aliases chunk
        if (n150 < regA_h + regB_h) n150 = regA_h + regB_h;
        if (h_avail >= fixed_h + n450)      P = 450;
        else if (h_avail >= fixed_h + n150) P = 150;
    }

    _Float16* D1 = ws + fixed_h;
    _Float16* D2 = D1 + (size_t)P * 676 * 512;

    // ---- precompute fp16 operands ----
    ring_zero<<<(2 * 772 * 16 + 255) / 256, 256, 0, stream>>>(X16i, 2, 194, 128);
    build_x16i<<<4608, 256, 0, stream>>>(src, tgt, X16i);
    cvt_w<<<2304, 256, 0, stream>>>(W1,  W1h,  512, 128);
    cvt_w<<<4608, 256, 0, stream>>>(W2,  W2h,  256, 512);
    cvt_w<<<2304, 256, 0, stream>>>(Wr1, Wr1h, 512, 128);
    cvt_w<<<1152, 256, 0, stream>>>(Wr2, Wr2h, 64,  512);
    cvt_pad16<<<(16 * 9 * 256 + 255) / 256, 256, 0, stream>>>(W3,  W3p,  256);
    cvt_pad16<<<(16 * 9 * 64  + 255) / 256, 256, 0, stream>>>(Wr3, Wr3p, 64);

    ring_zero<<<(P * 100 * 64 + 255) / 256, 256, 0, stream>>>(D1, P, 26, 512);
    ring_zero<<<(P * 100 * 32 + 255) / 256, 256, 0, stream>>>(D2, P, 26, 256);

    if (P == 450) {
        _Float16* A1 = D2 + (size_t)450 * 676 * 256;
        _Float16* A2 = A1 + regA_h;
        ring_zero<<<(2 * 772 * 64 + 255) / 256, 256, 0, stream>>>(A1, 2, 194, 512);
        ring_zero<<<(2 * 772 * 8  + 255) / 256, 256, 0, stream>>>(A2, 2, 194, 64);

        // merged conv1: 450 att patch-blocks + 128 reg image-tiles, one grid
        mfma_conv<4><<<swiz_grid(578, 8), 256, 0, stream>>>(
            X16i, W1h, b1, D1, Wr1h, br1, A1,
            128, 512, 194, 26, 194, 3, 578, 8, 0, 450);
        // att conv2 + score
        mfma_conv<4><<<swiz_grid(450, 4), 256, 0, stream>>>(
            D1, W2h, b2, D2, nullptr, nullptr, nullptr,
            512, 256, 26, 26, 26, 1, 450, 4, 0, 0);
        mfma_score<1, 1><<<450, 256, 0, stream>>>(D2, W3p, b3, score, 256, 26, 450);
        att_finalize<<<288, 256, 0, stream>>>(score, out + 73728);
        // reg conv2 + score
        mfma_conv<1><<<swiz_grid(128, 4), 256, 0, stream>>>(
            A1, Wr2h, br2, A2, nullptr, nullptr, nullptr,
            512, 64, 194, 194, 194, 2, 128, 4, 0, 0);
        mfma_score<2, 2><<<128, 256, 0, stream>>>(A2, Wr3p, br3, out, 64, 194, 128);
    } else {
        const int nchunks = 450 / P;
        for (int c = 0; c < nchunks; ++c) {
            int p0 = c * P;
            mfma_conv<4><<<swiz_grid(P, 8), 256, 0, stream>>>(
                X16i, W1h, b1, D1, nullptr, nullptr, nullptr,
                128, 512, 194, 26, 26, 0, P, 8, p0, 0);
            mfma_conv<4><<<swiz_grid(P, 4), 256, 0, stream>>>(
                D1, W2h, b2, D2, nullptr, nullptr, nullptr,
                512, 256, 26, 26, 26, 1, P, 4, 0, 0);
            mfma_score<1, 1><<<P, 256, 0, stream>>>(
                D2, W3p, b3, score + (size_t)p0 * 576, 256, 26, P);
        }
        att_finalize<<<288, 256, 0, stream>>>(score, out + 73728);

        if (P >= 150) {
            _Float16* A1 = ws + fixed_h;           // alias chunk region (att done)
            _Float16* A2 = A1 + regA_h;
            ring_zero<<<(2 * 772 * 64 + 255) / 256, 256, 0, stream>>>(A1, 2, 194, 512);
            ring_zero<<<(2 * 772 * 8  + 255) / 256, 256, 0, stream>>>(A2, 2, 194, 64);
            mfma_conv<4><<<swiz_grid(128, 8), 256, 0, stream>>>(
                X16i, Wr1h, br1, A1, nullptr, nullptr, nullptr,
                128, 512, 194, 194, 194, 2, 128, 8, 0, 0);
            mfma_conv<1><<<swiz_grid(128, 4), 256, 0, stream>>>(
                A1, Wr2h, br2, A2, nullptr, nullptr, nullptr,
                512, 64, 194, 194, 194, 2, 128, 4, 0, 0);
            mfma_score<2, 2><<<128, 256, 0, stream>>>(A2, Wr3p, br3, out, 64, 194, 128);
        } else {
            _Float16* A1 = ws + fixed_h;
            _Float16* A2 = A1 + (size_t)194 * 194 * 512;
            for (int b = 0; b < 2; ++b) {
                ring_zero<<<(772 * 64 + 255) / 256, 256, 0, stream>>>(A1, 1, 194, 512);
                ring_zero<<<(772 * 8  + 255) / 256, 256, 0, stream>>>(A2, 1, 194, 64);
                mfma_conv<4><<<swiz_grid(64, 8), 256, 0, stream>>>(
                    X16i + (size_t)b * 194 * 194 * 128, Wr1h, br1, A1,
                    nullptr, nullptr, nullptr,
                    128, 512, 194, 194, 194, 2, 64, 8, 0, 0);
                mfma_conv<1><<<swiz_grid(64, 4), 256, 0, stream>>>(
                    A1, Wr2h, br2, A2, nullptr, nullptr, nullptr,
                    512, 64, 194, 194, 194, 2, 64, 4, 0, 0);
                mfma_score<2, 2><<<64, 256, 0, stream>>>(
                    A2, Wr3p, br3, out + (size_t)b * 36864, 64, 194, 64);
            }
        }
    }
}

// Round 9
// 2499.484 us; speedup vs baseline: 1.4647x; 1.4647x over previous
//
#include <hip/hip_runtime.h>
#include <cmath>

typedef _Float16 half8  __attribute__((ext_vector_type(8)));
typedef _Float16 half4v __attribute__((ext_vector_type(4)));
typedef float    float4v __attribute__((ext_vector_type(4)));

// ---------------------------------------------------------------------------
// MFMA conv3x3 (SAME), fp16 in / fp32 acc / fp16 out (relu). R7 structure
// (two-barrier VGPR weight staging — R8's global_load_lds dbuf + vmcnt(0)
// REGRESSED; runtime dims — R6 templating regressed; launch_bounds (256,2) —
// (256,4) spilled accs, R3).
// R9: wave tile generalized to (MT*16) co x (NT*16) px. 4 waves stack on px:
// block = NT*64 px; a patch (576 px) = (9/NT) px-blocks. MT=8/NT=3 doubles
// FLOP per B-byte (65 -> 128) for the B-supply-bound big convs.
// XCD swizzle: all (pxb, co_t) variants of one patch adjacent on one XCD.
// ---------------------------------------------------------------------------
template<int MT, int NT>
__global__ __launch_bounds__(256, 2)
void mfma_conv(const _Float16* __restrict__ in, const _Float16* __restrict__ Wg,
               const float* __restrict__ bias, _Float16* __restrict__ out,
               int CI, int CO, int RSin, int RSout, int IMG, int NB, int NC)
{
    __shared__ __align__(16) _Float16 sW[9 * MT * 64 * 8];

    const int tid  = threadIdx.x;
    const int wave = tid >> 6;
    const int lane = tid & 63;
    const int ll   = lane & 15;
    const int quad = lane >> 4;

    const int NSUB = NC * (9 / NT);          // px-blocks x co-tiles per patch
    const int id   = blockIdx.x;
    const int xcd  = id & 7;
    const int slot = id >> 3;
    const int unit = (slot / NSUB) * 8 + xcd;    // patch / image-tile index
    const int rem  = slot % NSUB;
    const int pxb  = rem / NC;
    const int co_t = rem % NC;
    if (unit >= NB) return;
    const int co0 = co_t * (MT * 16);
    const int pbase = pxb * (NT * 64) + wave * (NT * 16);

    size_t in_base, out_base;
    int TY = 0, TX = 0;
    if (IMG) {
        int tile = unit & 63, b = unit >> 6;
        TY = (tile >> 3) * 24; TX = (tile & 7) * 24;
        in_base  = (size_t)b * RSin * RSin * CI;
        out_base = (size_t)b * RSout * RSout * CO;
    } else {
        in_base  = (size_t)unit * 676 * CI;
        out_base = (size_t)unit * 676 * CO;
    }

    int b_off[NT];
    #pragma unroll
    for (int nt = 0; nt < NT; ++nt) {
        int p = pbase + nt * 16 + ll;
        b_off[nt] = ((TY + p / 24) * RSin + (TX + p % 24)) * CI;
    }
    int tapoff[9];
    #pragma unroll
    for (int dy = 0; dy < 3; ++dy)
        #pragma unroll
        for (int dx = 0; dx < 3; ++dx)
            tapoff[dy * 3 + dx] = (dy * RSin + dx) * CI;

    float4v acc[MT][NT];
    #pragma unroll
    for (int mt = 0; mt < MT; ++mt)
        #pragma unroll
        for (int nt = 0; nt < NT; ++nt)
            acc[mt][nt] = (float4v){0.f, 0.f, 0.f, 0.f};

    for (int ci0 = 0; ci0 < CI; ci0 += 32) {
        __syncthreads();
        // stage weights in read-order: slot c = (t*MT+mt)*64 + lane (conflict-free)
        for (int c = tid; c < 9 * MT * 64; c += 256) {
            int lane_s = c & 63;
            int mtt = c >> 6;
            int mt = mtt % MT, t = mtt / MT;
            *(uint4*)&sW[(size_t)c * 8] =
                *(const uint4*)&Wg[((size_t)(co0 + mt * 16 + (lane_s & 15)) * 9 + t) * CI
                                   + ci0 + (lane_s >> 4) * 8];
        }
        __syncthreads();

        const _Float16* inp = in + in_base + ci0 + quad * 8;
        #pragma unroll
        for (int t = 0; t < 9; ++t) {
            half8 a[MT];
            #pragma unroll
            for (int mt = 0; mt < MT; ++mt)
                a[mt] = *(const half8*)&sW[((t * MT + mt) * 64 + lane) * 8];
            const int toff = tapoff[t];
            #pragma unroll
            for (int nt = 0; nt < NT; ++nt) {
                half8 b = *(const half8*)(inp + b_off[nt] + toff);
                #pragma unroll
                for (int mt = 0; mt < MT; ++mt)
                    acc[mt][nt] = __builtin_amdgcn_mfma_f32_16x16x32_f16(
                        a[mt], b, acc[mt][nt], 0, 0, 0);
            }
        }
    }

    // epilogue: bias + relu -> fp16; D layout col=lane&15 (px), row=quad*4+reg
    #pragma unroll
    for (int mt = 0; mt < MT; ++mt) {
        float4v bs = *(const float4v*)&bias[co0 + mt * 16 + quad * 4];
        #pragma unroll
        for (int nt = 0; nt < NT; ++nt) {
            int p = pbase + nt * 16 + ll;
            size_t ooff = out_base
                + (size_t)((TY + p / 24 + 1) * RSout + (TX + p % 24) + 1) * CO
                + co0 + mt * 16 + quad * 4;
            float4v v = acc[mt][nt];
            half4v h;
            h.x = (_Float16)fmaxf(v.x + bs.x, 0.f);
            h.y = (_Float16)fmaxf(v.y + bs.y, 0.f);
            h.z = (_Float16)fmaxf(v.z + bs.z, 0.f);
            h.w = (_Float16)fmaxf(v.w + bs.w, 0.f);
            *(half4v*)(out + ooff) = h;
        }
    }
}

static inline int swiz_grid(int NB, int NC, int PXB) {
    return ((NB + 7) & ~7) * NC * PXB;
}

// ---------------------------------------------------------------------------
// M=1 conv3 via MFMA, CO padded to 16 (rows 1..15 zero). Runtime CI/RSI.
// MODE 1: patch buffer [NB][26][26][CI]; ACT 1: sigmoid -> outp[blk*576+p]
// MODE 2: image [b][RSI][RSI][CI];       ACT 2: tanh    -> outp[b*36864+...]
// ---------------------------------------------------------------------------
template<int MODE, int ACT>
__global__ __launch_bounds__(256, 2)
void mfma_score(const _Float16* __restrict__ in, const _Float16* __restrict__ W16,
                const float* __restrict__ bias, float* __restrict__ outp,
                int CI, int RSI, int NB)
{
    __shared__ __align__(16) _Float16 sW[9 * 16 * 32];

    const int tid  = threadIdx.x;
    const int wave = tid >> 6;
    const int lane = tid & 63;
    const int ll   = lane & 15;
    const int quad = lane >> 4;

    const int blk = blockIdx.x;
    if (blk >= NB) return;

    size_t in_base;
    int ty = 0, tx = 0, bb = 0;
    if (MODE == 2) {
        bb = blk >> 6; int tile = blk & 63; ty = tile >> 3; tx = tile & 7;
        in_base = (size_t)bb * RSI * RSI * CI;
    } else {
        in_base = (size_t)blk * 676 * CI;
    }

    int b_off[9];
    #pragma unroll
    for (int nt = 0; nt < 9; ++nt) {
        int p = wave * 144 + nt * 16 + ll;
        int py = p / 24, px = p % 24;
        b_off[nt] = (MODE == 2) ? ((ty * 24 + py) * RSI + (tx * 24 + px)) * CI
                                : (py * RSI + px) * CI;
    }

    float4v acc[9];
    #pragma unroll
    for (int nt = 0; nt < 9; ++nt) acc[nt] = (float4v){0.f, 0.f, 0.f, 0.f};

    for (int ci0 = 0; ci0 < CI; ci0 += 32) {
        __syncthreads();
        for (int c = tid; c < 9 * 16 * 4; c += 256) {
            int q = c & 3, tco = c >> 2;
            int t = tco >> 4, co = tco & 15;
            *(uint4*)&sW[tco * 32 + q * 8] =
                *(const uint4*)&W16[((size_t)co * 9 + t) * CI + ci0 + q * 8];
        }
        __syncthreads();

        const _Float16* inp = in + in_base + ci0 + quad * 8;
        for (int dy = 0; dy < 3; ++dy)
            for (int dx = 0; dx < 3; ++dx) {
                const int t = dy * 3 + dx;
                const int toff = (dy * RSI + dx) * CI;
                half8 a = *(const half8*)&sW[(t * 16 + ll) * 32 + quad * 8];
                #pragma unroll
                for (int nt = 0; nt < 9; ++nt) {
                    half8 b = *(const half8*)(inp + b_off[nt] + toff);
                    acc[nt] = __builtin_amdgcn_mfma_f32_16x16x32_f16(a, b, acc[nt], 0, 0, 0);
                }
            }
    }

    if (quad == 0) {
        float bv = bias[0];
        #pragma unroll
        for (int nt = 0; nt < 9; ++nt) {
            int p = wave * 144 + nt * 16 + ll;
            float v = acc[nt].x + bv;
            if (ACT == 1) {
                outp[(size_t)blk * 576 + p] = 1.f / (1.f + expf(-v));
            } else {
                int y = ty * 24 + p / 24, x = tx * 24 + p % 24;
                outp[(size_t)bb * 36864 + y * 192 + x] = tanhf(v);
            }
        }
    }
}

// ---------------------------------------------------------------------------
// helpers
// ---------------------------------------------------------------------------
__global__ __launch_bounds__(256)
void build_x16i(const float* __restrict__ src, const float* __restrict__ tgt,
                _Float16* __restrict__ X)
{
    int idx = blockIdx.x * 256 + threadIdx.x;
    int q = idx & 15, pid = idx >> 4;
    if (pid >= 2 * 36864) return;
    int b = pid / 36864, r = pid % 36864;
    int y = r / 192, x = r % 192;
    half8 h;
    #pragma unroll
    for (int j = 0; j < 8; ++j) {
        int ch = q * 8 + j;
        const float* im = (ch < 64) ? src : tgt;
        h[j] = (_Float16)im[(size_t)(b * 64 + (ch & 63)) * 36864 + r];
    }
    *(half8*)&X[(((size_t)b * 194 + y + 1) * 194 + (x + 1)) * 128 + q * 8] = h;
}

__global__ __launch_bounds__(256)
void cvt_w(const float* __restrict__ src, _Float16* __restrict__ dst, int CO, int CI)
{
    int idx = blockIdx.x * 256 + threadIdx.x;
    if (idx >= CO * 9 * CI) return;
    int ci = idx % CI, t = (idx / CI) % 9, co = idx / (9 * CI);
    dst[idx] = (_Float16)src[((size_t)co * CI + ci) * 9 + t];
}

__global__ __launch_bounds__(256)
void cvt_pad16(const float* __restrict__ src, _Float16* __restrict__ dst, int CI)
{
    int idx = blockIdx.x * 256 + threadIdx.x;
    if (idx >= 16 * 9 * CI) return;
    int ci = idx % CI, t = (idx / CI) % 9, co = idx / (9 * CI);
    dst[idx] = (co == 0) ? (_Float16)src[(size_t)ci * 9 + t] : (_Float16)0.0f;
}

__global__ __launch_bounds__(256)
void g_patch(const _Float16* __restrict__ X, _Float16* __restrict__ P1, int p0, int nP)
{
    int idx = blockIdx.x * 256 + threadIdx.x;
    if (idx >= nP * 676 * 16) return;
    int q = idx & 15, t2 = idx >> 4;
    int r676 = t2 % 676, pl = t2 / 676;
    int pr = r676 / 26, pc = r676 % 26;
    int P = p0 + pl;
    int b = P / 225, rem = P % 225, pi = rem / 15, pj = rem % 15;
    uint4 v = {0u, 0u, 0u, 0u};
    if (pr >= 1 && pr <= 24 && pc >= 1 && pc <= 24)
        v = *(const uint4*)&X[(((size_t)b * 194 + pi * 12 + pr) * 194 + (pj * 12 + pc)) * 128 + q * 8];
    *(uint4*)&P1[((size_t)pl * 676 + r676) * 128 + q * 8] = v;
}

__global__ __launch_bounds__(256)
void ring_zero(_Float16* __restrict__ buf, int npatch, int RS, int CI)
{
    int c8 = CI >> 3;
    int RC = 2 * RS + 2 * (RS - 2);
    int idx = blockIdx.x * 256 + threadIdx.x;
    if (idx >= npatch * RC * c8) return;
    int q = idx % c8, rp = (idx / c8) % RC, pl = idx / (c8 * RC);
    int r, c;
    if (rp < RS)            { r = 0;      c = rp; }
    else if (rp < 2 * RS)   { r = RS - 1; c = rp - RS; }
    else {
        int s = rp - 2 * RS, half = RS - 2;
        if (s < half) { r = s + 1;        c = 0; }
        else          { r = s - half + 1; c = RS - 1; }
    }
    uint4 z = {0u, 0u, 0u, 0u};
    *(uint4*)&buf[((size_t)pl * RS * RS + r * RS + c) * CI + q * 8] = z;
}

__global__ __launch_bounds__(256)
void att_finalize(const float* __restrict__ score, float* __restrict__ out)
{
    int idx = blockIdx.x * 256 + threadIdx.x;
    if (idx >= 2 * 36864) return;
    int b = idx / 36864, r = idx % 36864;
    int y = r / 192, x = r % 192;
    int i_lo = (y >= 24) ? (y - 12) / 12 : 0;
    int i_hi = min(14, y / 12);
    int j_lo = (x >= 24) ? (x - 12) / 12 : 0;
    int j_hi = min(14, x / 12);
    float s = 0.f; int cnt = 0;
    for (int i = i_lo; i <= i_hi; ++i)
        for (int j = j_lo; j <= j_hi; ++j) {
            s += score[(((size_t)b * 15 + i) * 15 + j) * 576 + (y - 12 * i) * 24 + (x - 12 * j)];
            ++cnt;
        }
    out[idx] = s / (float)cnt;
}

// ---------------------------------------------------------------------------
extern "C" void kernel_launch(void* const* d_in, const int* in_sizes, int n_in,
                              void* d_out, int out_size, void* d_ws, size_t ws_size,
                              hipStream_t stream)
{
    const float* src = (const float*)d_in[0];
    const float* tgt = (const float*)d_in[1];
    const float* W1  = (const float*)d_in[2];  const float* b1  = (const float*)d_in[3];
    const float* W2  = (const float*)d_in[4];  const float* b2  = (const float*)d_in[5];
    const float* W3  = (const float*)d_in[6];  const float* b3  = (const float*)d_in[7];
    const float* Wr1 = (const float*)d_in[8];  const float* br1 = (const float*)d_in[9];
    const float* Wr2 = (const float*)d_in[10]; const float* br2 = (const float*)d_in[11];
    const float* Wr3 = (const float*)d_in[12]; const float* br3 = (const float*)d_in[13];
    float* out = (float*)d_out;

    // ---- fixed workspace (halves) ----
    _Float16* ws = (_Float16*)d_ws;
    size_t o = 0;
    _Float16* X16i = ws + o; o += (size_t)2 * 194 * 194 * 128;
    _Float16* W1h  = ws + o; o += (size_t)512 * 9 * 128;
    _Float16* W2h  = ws + o; o += (size_t)256 * 9 * 512;
    _Float16* Wr1h = ws + o; o += (size_t)512 * 9 * 128;
    _Float16* Wr2h = ws + o; o += (size_t)64 * 9 * 512;
    _Float16* W3p  = ws + o; o += (size_t)16 * 9 * 256;
    _Float16* Wr3p = ws + o; o += (size_t)16 * 9 * 64;
    float*    score = (float*)(ws + o); o += 2 * 259200;
    const size_t fixed_h = o;

    // ---- adaptive patch chunking ----
    const size_t per_patch_h = (size_t)676 * (128 + 512 + 256);  // 605,696
    const size_t regA_h = (size_t)2 * 194 * 194 * 512;
    const size_t regB_h = (size_t)2 * 194 * 194 * 64;
    size_t h_avail = ws_size / 2;
    int P = 50;
    {
        size_t n450 = 450 * per_patch_h; if (n450 < regA_h + regB_h) n450 = regA_h + regB_h;
        size_t n150 = 150 * per_patch_h; if (n150 < regA_h + regB_h) n150 = regA_h + regB_h;
        if (h_avail >= fixed_h + n450)      P = 450;
        else if (h_avail >= fixed_h + n150) P = 150;
    }
    const int nchunks = 450 / P;

    _Float16* P1 = ws + fixed_h;
    _Float16* D1 = P1 + (size_t)P * 676 * 128;
    _Float16* D2 = D1 + (size_t)P * 676 * 512;

    // ---- precompute fp16 operands ----
    ring_zero<<<(2 * 772 * 16 + 255) / 256, 256, 0, stream>>>(X16i, 2, 194, 128);
    build_x16i<<<4608, 256, 0, stream>>>(src, tgt, X16i);
    cvt_w<<<2304, 256, 0, stream>>>(W1,  W1h,  512, 128);
    cvt_w<<<4608, 256, 0, stream>>>(W2,  W2h,  256, 512);
    cvt_w<<<2304, 256, 0, stream>>>(Wr1, Wr1h, 512, 128);
    cvt_w<<<1152, 256, 0, stream>>>(Wr2, Wr2h, 64,  512);
    cvt_pad16<<<(16 * 9 * 256 + 255) / 256, 256, 0, stream>>>(W3,  W3p,  256);
    cvt_pad16<<<(16 * 9 * 64  + 255) / 256, 256, 0, stream>>>(Wr3, Wr3p, 64);

    // ---- attention path ----
    ring_zero<<<(P * 100 * 64 + 255) / 256, 256, 0, stream>>>(D1, P, 26, 512);
    ring_zero<<<(P * 100 * 32 + 255) / 256, 256, 0, stream>>>(D2, P, 26, 256);
    for (int c = 0; c < nchunks; ++c) {
        int p0 = c * P;
        g_patch<<<(P * 676 * 16 + 255) / 256, 256, 0, stream>>>(X16i, P1, p0, P);
        // conv1: 128->512, MT=8 (128 co/wave) x NT=3 (192 px/block), NC=4
        mfma_conv<8, 3><<<swiz_grid(P, 4, 3), 256, 0, stream>>>(
            P1, W1h, b1, D1, 128, 512, 26, 26, 0, P, 4);
        // conv2: 512->256, MT=8 x NT=3, NC=2
        mfma_conv<8, 3><<<swiz_grid(P, 2, 3), 256, 0, stream>>>(
            D1, W2h, b2, D2, 512, 256, 26, 26, 0, P, 2);
        mfma_score<1, 1><<<P, 256, 0, stream>>>(D2, W3p, b3, score + (size_t)p0 * 576, 256, 26, P);
    }
    att_finalize<<<288, 256, 0, stream>>>(score, out + 73728);

    // ---- registration path (R7-proven shapes) ----
    if (P >= 150) {
        _Float16* A1 = ws + fixed_h;           // alias chunk region (att done)
        _Float16* A2 = A1 + regA_h;
        ring_zero<<<(2 * 772 * 64 + 255) / 256, 256, 0, stream>>>(A1, 2, 194, 512);
        ring_zero<<<(2 * 772 * 8  + 255) / 256, 256, 0, stream>>>(A2, 2, 194, 64);
        mfma_conv<4, 9><<<swiz_grid(128, 8, 1), 256, 0, stream>>>(
            X16i, Wr1h, br1, A1, 128, 512, 194, 194, 1, 128, 8);
        mfma_conv<2, 9><<<swiz_grid(128, 2, 1), 256, 0, stream>>>(
            A1, Wr2h, br2, A2, 512, 64, 194, 194, 1, 128, 2);
        mfma_score<2, 2><<<128, 256, 0, stream>>>(A2, Wr3p, br3, out, 64, 194, 128);
    } else {
        _Float16* A1 = ws + fixed_h;
        _Float16* A2 = A1 + (size_t)194 * 194 * 512;
        for (int b = 0; b < 2; ++b) {
            ring_zero<<<(772 * 64 + 255) / 256, 256, 0, stream>>>(A1, 1, 194, 512);
            ring_zero<<<(772 * 8  + 255) / 256, 256, 0, stream>>>(A2, 1, 194, 64);
            mfma_conv<4, 9><<<swiz_grid(64, 8, 1), 256, 0, stream>>>(
                X16i + (size_t)b * 194 * 194 * 128, Wr1h, br1, A1,
                128, 512, 194, 194, 1, 64, 8);
            mfma_conv<2, 9><<<swiz_grid(64, 2, 1), 256, 0, stream>>>(
                A1, Wr2h, br2, A2, 512, 64, 194, 194, 1, 64, 2);
            mfma_score<2, 2><<<64, 256, 0, stream>>>(A2, Wr3p, br3, out + (size_t)b * 36864, 64, 194, 64);
        }
    }
}

// Round 10
// 2303.773 us; speedup vs baseline: 1.5891x; 1.0850x over previous
//
#include <hip/hip_runtime.h>
#include <cmath>

typedef _Float16 half8  __attribute__((ext_vector_type(8)));
typedef _Float16 half4v __attribute__((ext_vector_type(4)));
typedef float    float4v __attribute__((ext_vector_type(4)));

// ---------------------------------------------------------------------------
// MFMA conv3x3 (SAME), fp16 in / fp32 acc / fp16 out (relu).
// Wave tile = (MT*16) co x (NT*16) px; 4 waves stack on px (block = NT*64 px).
// MT=8/NT=3 = 131 FLOP/B-byte (R9: conv2 572->391 us, 63% of MFMA floor).
// Runtime dims (R6: templating CI bloats VGPR +23%); launch_bounds (256,2)
// (R3: (256,4) spills accs); A via LDS read-order (0 bank conflicts);
// XCD swizzle keeps all sub-blocks of one patch/tile on one XCD (R5).
// R8's global_load_lds dbuf + vmcnt(0) regressed — two-barrier staging kept.
// MODE 0: att patch conv reading padded IMAGE directly; per-lane edge masks
//         emulate per-patch SAME zero-pad (validated R6/R8; kills g_patch).
// MODE 1: patch buffer [NB][26][26][CI] (ring zeroed).
// MODE 2: image [b][RSin][RSin][CI]; unit = b*64 + tile.
// ---------------------------------------------------------------------------
template<int MT, int NT, int MODE>
__global__ __launch_bounds__(256, 2)
void mfma_conv(const _Float16* __restrict__ in, const _Float16* __restrict__ Wg,
               const float* __restrict__ bias, _Float16* __restrict__ out,
               int CI, int CO, int RSin, int RSout, int NB, int NC, int p0)
{
    __shared__ __align__(16) _Float16 sW[9 * MT * 64 * 8];

    const int tid  = threadIdx.x;
    const int wave = tid >> 6;
    const int lane = tid & 63;
    const int ll   = lane & 15;
    const int quad = lane >> 4;

    const int NSUB = NC * (9 / NT);
    const int id   = blockIdx.x;
    const int xcd  = id & 7;
    const int slot = id >> 3;
    const int unit = (slot / NSUB) * 8 + xcd;
    const int rem  = slot % NSUB;
    const int pxb  = rem / NC;
    const int co_t = rem % NC;
    if (unit >= NB) return;
    const int co0 = co_t * (MT * 16);
    const int pbase = pxb * (NT * 64) + wave * (NT * 16);

    size_t in_base, out_base;
    int TY = 0, TX = 0;
    int b_off[NT], edge[NT];
    if (MODE == 0) {
        int pat = p0 + unit;
        int bb = pat / 225, remp = pat % 225;
        int pi = remp / 15, pj = remp % 15;
        in_base  = (size_t)bb * RSin * RSin * CI;
        out_base = (size_t)unit * 676 * CO;
        #pragma unroll
        for (int nt = 0; nt < NT; ++nt) {
            int p = pbase + nt * 16 + ll;
            int py = p / 24, px = p % 24;
            b_off[nt] = ((pi * 12 + py) * RSin + (pj * 12 + px)) * CI;
            edge[nt] = (py == 0 ? 1 : 0) | (py == 23 ? 2 : 0)
                     | (px == 0 ? 4 : 0) | (px == 23 ? 8 : 0);
        }
    } else if (MODE == 1) {
        in_base  = (size_t)unit * 676 * CI;
        out_base = (size_t)unit * 676 * CO;
        #pragma unroll
        for (int nt = 0; nt < NT; ++nt) {
            int p = pbase + nt * 16 + ll;
            b_off[nt] = ((p / 24) * RSin + (p % 24)) * CI;
            edge[nt] = 0;
        }
    } else {
        int tile = unit & 63, b = unit >> 6;
        TY = (tile >> 3) * 24; TX = (tile & 7) * 24;
        in_base  = (size_t)b * RSin * RSin * CI;
        out_base = (size_t)b * RSout * RSout * CO;
        #pragma unroll
        for (int nt = 0; nt < NT; ++nt) {
            int p = pbase + nt * 16 + ll;
            b_off[nt] = ((TY + p / 24) * RSin + (TX + p % 24)) * CI;
            edge[nt] = 0;
        }
    }

    float4v acc[MT][NT];
    #pragma unroll
    for (int mt = 0; mt < MT; ++mt)
        #pragma unroll
        for (int nt = 0; nt < NT; ++nt)
            acc[mt][nt] = (float4v){0.f, 0.f, 0.f, 0.f};

    for (int ci0 = 0; ci0 < CI; ci0 += 32) {
        __syncthreads();
        for (int c = tid; c < 9 * MT * 64; c += 256) {
            int lane_s = c & 63;
            int mtt = c >> 6;
            int mt = mtt % MT, t = mtt / MT;
            *(uint4*)&sW[(size_t)c * 8] =
                *(const uint4*)&Wg[((size_t)(co0 + mt * 16 + (lane_s & 15)) * 9 + t) * CI
                                   + ci0 + (lane_s >> 4) * 8];
        }
        __syncthreads();

        const _Float16* inp = in + in_base + ci0 + quad * 8;
        #pragma unroll
        for (int dy = 0; dy < 3; ++dy) {
            #pragma unroll
            for (int dx = 0; dx < 3; ++dx) {
                const int t = dy * 3 + dx;
                const int toff = (dy * RSin + dx) * CI;
                const int emask = (dy == 0 ? 1 : 0) | (dy == 2 ? 2 : 0)
                                | (dx == 0 ? 4 : 0) | (dx == 2 ? 8 : 0);
                half8 a[MT];
                #pragma unroll
                for (int mt = 0; mt < MT; ++mt)
                    a[mt] = *(const half8*)&sW[((t * MT + mt) * 64 + lane) * 8];
                #pragma unroll
                for (int nt = 0; nt < NT; ++nt) {
                    uint4 raw = *(const uint4*)(inp + b_off[nt] + toff);
                    if (MODE == 0) {
                        bool z = (edge[nt] & emask) != 0;
                        raw.x = z ? 0u : raw.x;
                        raw.y = z ? 0u : raw.y;
                        raw.z = z ? 0u : raw.z;
                        raw.w = z ? 0u : raw.w;
                    }
                    half8 b = *(half8*)&raw;
                    #pragma unroll
                    for (int mt = 0; mt < MT; ++mt)
                        acc[mt][nt] = __builtin_amdgcn_mfma_f32_16x16x32_f16(
                            a[mt], b, acc[mt][nt], 0, 0, 0);
                }
            }
        }
    }

    // epilogue: bias + relu -> fp16; D layout col=lane&15 (px), row=quad*4+reg
    #pragma unroll
    for (int mt = 0; mt < MT; ++mt) {
        float4v bs = *(const float4v*)&bias[co0 + mt * 16 + quad * 4];
        #pragma unroll
        for (int nt = 0; nt < NT; ++nt) {
            int p = pbase + nt * 16 + ll;
            size_t ooff = out_base
                + (size_t)((TY + p / 24 + 1) * RSout + (TX + p % 24) + 1) * CO
                + co0 + mt * 16 + quad * 4;
            float4v v = acc[mt][nt];
            half4v h;
            h.x = (_Float16)fmaxf(v.x + bs.x, 0.f);
            h.y = (_Float16)fmaxf(v.y + bs.y, 0.f);
            h.z = (_Float16)fmaxf(v.z + bs.z, 0.f);
            h.w = (_Float16)fmaxf(v.w + bs.w, 0.f);
            *(half4v*)(out + ooff) = h;
        }
    }
}

static inline int swiz_grid(int NB, int NC, int PXB) {
    return ((NB + 7) & ~7) * NC * PXB;
}

// ---------------------------------------------------------------------------
// M=1 conv3 via MFMA, CO padded to 16 (rows 1..15 zero). Runtime CI/RSI.
// NT n-tiles per wave, PXB px-blocks: grid = NB*PXB; unit = id/PXB.
// MODE 1: patch buffer [NB][26][26][CI]; ACT 1: sigmoid -> outp[unit*576+p]
// MODE 2: image [b][RSI][RSI][CI];       ACT 2: tanh    -> outp[b*36864+...]
// ---------------------------------------------------------------------------
template<int MODE, int ACT, int NT>
__global__ __launch_bounds__(256, 2)
void mfma_score(const _Float16* __restrict__ in, const _Float16* __restrict__ W16,
                const float* __restrict__ bias, float* __restrict__ outp,
                int CI, int RSI, int NB, int PXB)
{
    __shared__ __align__(16) _Float16 sW[9 * 16 * 32];

    const int tid  = threadIdx.x;
    const int wave = tid >> 6;
    const int lane = tid & 63;
    const int ll   = lane & 15;
    const int quad = lane >> 4;

    const int unit = blockIdx.x / PXB;
    const int pxb  = blockIdx.x % PXB;
    if (unit >= NB) return;
    const int pbase = pxb * (NT * 64) + wave * (NT * 16);

    size_t in_base;
    int ty = 0, tx = 0, bb = 0;
    if (MODE == 2) {
        bb = unit >> 6; int tile = unit & 63; ty = (tile >> 3) * 24; tx = (tile & 7) * 24;
        in_base = (size_t)bb * RSI * RSI * CI;
    } else {
        in_base = (size_t)unit * 676 * CI;
    }

    int b_off[NT];
    #pragma unroll
    for (int nt = 0; nt < NT; ++nt) {
        int p = pbase + nt * 16 + ll;
        b_off[nt] = ((ty + p / 24) * RSI + (tx + p % 24)) * CI;
    }

    float4v acc[NT];
    #pragma unroll
    for (int nt = 0; nt < NT; ++nt) acc[nt] = (float4v){0.f, 0.f, 0.f, 0.f};

    for (int ci0 = 0; ci0 < CI; ci0 += 32) {
        __syncthreads();
        for (int c = tid; c < 9 * 16 * 4; c += 256) {
            int q = c & 3, tco = c >> 2;
            int t = tco >> 4, co = tco & 15;
            *(uint4*)&sW[tco * 32 + q * 8] =
                *(const uint4*)&W16[((size_t)co * 9 + t) * CI + ci0 + q * 8];
        }
        __syncthreads();

        const _Float16* inp = in + in_base + ci0 + quad * 8;
        for (int dy = 0; dy < 3; ++dy)
            for (int dx = 0; dx < 3; ++dx) {
                const int t = dy * 3 + dx;
                const int toff = (dy * RSI + dx) * CI;
                half8 a = *(const half8*)&sW[(t * 16 + ll) * 32 + quad * 8];
                #pragma unroll
                for (int nt = 0; nt < NT; ++nt) {
                    half8 b = *(const half8*)(inp + b_off[nt] + toff);
                    acc[nt] = __builtin_amdgcn_mfma_f32_16x16x32_f16(a, b, acc[nt], 0, 0, 0);
                }
            }
    }

    if (quad == 0) {
        float bv = bias[0];
        #pragma unroll
        for (int nt = 0; nt < NT; ++nt) {
            int p = pbase + nt * 16 + ll;
            float v = acc[nt].x + bv;
            if (ACT == 1) {
                outp[(size_t)unit * 576 + p] = 1.f / (1.f + expf(-v));
            } else {
                int y = ty + p / 24, x = tx + p % 24;
                outp[(size_t)bb * 36864 + y * 192 + x] = tanhf(v);
            }
        }
    }
}

// ---------------------------------------------------------------------------
// helpers
// ---------------------------------------------------------------------------
__global__ __launch_bounds__(256)
void build_x16i(const float* __restrict__ src, const float* __restrict__ tgt,
                _Float16* __restrict__ X)
{
    int idx = blockIdx.x * 256 + threadIdx.x;
    int q = idx & 15, pid = idx >> 4;
    if (pid >= 2 * 36864) return;
    int b = pid / 36864, r = pid % 36864;
    int y = r / 192, x = r % 192;
    half8 h;
    #pragma unroll
    for (int j = 0; j < 8; ++j) {
        int ch = q * 8 + j;
        const float* im = (ch < 64) ? src : tgt;
        h[j] = (_Float16)im[(size_t)(b * 64 + (ch & 63)) * 36864 + r];
    }
    *(half8*)&X[(((size_t)b * 194 + y + 1) * 194 + (x + 1)) * 128 + q * 8] = h;
}

__global__ __launch_bounds__(256)
void cvt_w(const float* __restrict__ src, _Float16* __restrict__ dst, int CO, int CI)
{
    int idx = blockIdx.x * 256 + threadIdx.x;
    if (idx >= CO * 9 * CI) return;
    int ci = idx % CI, t = (idx / CI) % 9, co = idx / (9 * CI);
    dst[idx] = (_Float16)src[((size_t)co * CI + ci) * 9 + t];
}

__global__ __launch_bounds__(256)
void cvt_pad16(const float* __restrict__ src, _Float16* __restrict__ dst, int CI)
{
    int idx = blockIdx.x * 256 + threadIdx.x;
    if (idx >= 16 * 9 * CI) return;
    int ci = idx % CI, t = (idx / CI) % 9, co = idx / (9 * CI);
    dst[idx] = (co == 0) ? (_Float16)src[(size_t)ci * 9 + t] : (_Float16)0.0f;
}

__global__ __launch_bounds__(256)
void ring_zero(_Float16* __restrict__ buf, int npatch, int RS, int CI)
{
    int c8 = CI >> 3;
    int RC = 2 * RS + 2 * (RS - 2);
    int idx = blockIdx.x * 256 + threadIdx.x;
    if (idx >= npatch * RC * c8) return;
    int q = idx % c8, rp = (idx / c8) % RC, pl = idx / (c8 * RC);
    int r, c;
    if (rp < RS)            { r = 0;      c = rp; }
    else if (rp < 2 * RS)   { r = RS - 1; c = rp - RS; }
    else {
        int s = rp - 2 * RS, half = RS - 2;
        if (s < half) { r = s + 1;        c = 0; }
        else          { r = s - half + 1; c = RS - 1; }
    }
    uint4 z = {0u, 0u, 0u, 0u};
    *(uint4*)&buf[((size_t)pl * RS * RS + r * RS + c) * CI + q * 8] = z;
}

__global__ __launch_bounds__(256)
void att_finalize(const float* __restrict__ score, float* __restrict__ out)
{
    int idx = blockIdx.x * 256 + threadIdx.x;
    if (idx >= 2 * 36864) return;
    int b = idx / 36864, r = idx % 36864;
    int y = r / 192, x = r % 192;
    int i_lo = (y >= 24) ? (y - 12) / 12 : 0;
    int i_hi = min(14, y / 12);
    int j_lo = (x >= 24) ? (x - 12) / 12 : 0;
    int j_hi = min(14, x / 12);
    float s = 0.f; int cnt = 0;
    for (int i = i_lo; i <= i_hi; ++i)
        for (int j = j_lo; j <= j_hi; ++j) {
            s += score[(((size_t)b * 15 + i) * 15 + j) * 576 + (y - 12 * i) * 24 + (x - 12 * j)];
            ++cnt;
        }
    out[idx] = s / (float)cnt;
}

// ---------------------------------------------------------------------------
extern "C" void kernel_launch(void* const* d_in, const int* in_sizes, int n_in,
                              void* d_out, int out_size, void* d_ws, size_t ws_size,
                              hipStream_t stream)
{
    const float* src = (const float*)d_in[0];
    const float* tgt = (const float*)d_in[1];
    const float* W1  = (const float*)d_in[2];  const float* b1  = (const float*)d_in[3];
    const float* W2  = (const float*)d_in[4];  const float* b2  = (const float*)d_in[5];
    const float* W3  = (const float*)d_in[6];  const float* b3  = (const float*)d_in[7];
    const float* Wr1 = (const float*)d_in[8];  const float* br1 = (const float*)d_in[9];
    const float* Wr2 = (const float*)d_in[10]; const float* br2 = (const float*)d_in[11];
    const float* Wr3 = (const float*)d_in[12]; const float* br3 = (const float*)d_in[13];
    float* out = (float*)d_out;

    // ---- fixed workspace (halves) ----
    _Float16* ws = (_Float16*)d_ws;
    size_t o = 0;
    _Float16* X16i = ws + o; o += (size_t)2 * 194 * 194 * 128;
    _Float16* W1h  = ws + o; o += (size_t)512 * 9 * 128;
    _Float16* W2h  = ws + o; o += (size_t)256 * 9 * 512;
    _Float16* Wr1h = ws + o; o += (size_t)512 * 9 * 128;
    _Float16* Wr2h = ws + o; o += (size_t)64 * 9 * 512;
    _Float16* W3p  = ws + o; o += (size_t)16 * 9 * 256;
    _Float16* Wr3p = ws + o; o += (size_t)16 * 9 * 64;
    float*    score = (float*)(ws + o); o += 2 * 259200;
    const size_t fixed_h = o;

    // ---- adaptive patch chunking (no P1: conv1 reads the image, MODE0) ----
    const size_t per_patch_h = (size_t)676 * (512 + 256);        // 519,168
    const size_t regA_h = (size_t)2 * 194 * 194 * 512;
    const size_t regB_h = (size_t)2 * 194 * 194 * 64;
    size_t h_avail = ws_size / 2;
    int P = 50;
    {
        size_t n450 = 450 * per_patch_h; if (n450 < regA_h + regB_h) n450 = regA_h + regB_h;
        size_t n150 = 150 * per_patch_h; if (n150 < regA_h + regB_h) n150 = regA_h + regB_h;
        if (h_avail >= fixed_h + n450)      P = 450;
        else if (h_avail >= fixed_h + n150) P = 150;
    }
    const int nchunks = 450 / P;

    _Float16* D1 = ws + fixed_h;
    _Float16* D2 = D1 + (size_t)P * 676 * 512;

    // ---- precompute fp16 operands ----
    ring_zero<<<(2 * 772 * 16 + 255) / 256, 256, 0, stream>>>(X16i, 2, 194, 128);
    build_x16i<<<4608, 256, 0, stream>>>(src, tgt, X16i);
    cvt_w<<<2304, 256, 0, stream>>>(W1,  W1h,  512, 128);
    cvt_w<<<4608, 256, 0, stream>>>(W2,  W2h,  256, 512);
    cvt_w<<<2304, 256, 0, stream>>>(Wr1, Wr1h, 512, 128);
    cvt_w<<<1152, 256, 0, stream>>>(Wr2, Wr2h, 64,  512);
    cvt_pad16<<<(16 * 9 * 256 + 255) / 256, 256, 0, stream>>>(W3,  W3p,  256);
    cvt_pad16<<<(16 * 9 * 64  + 255) / 256, 256, 0, stream>>>(Wr3, Wr3p, 64);

    // ---- attention path ----
    ring_zero<<<(P * 100 * 64 + 255) / 256, 256, 0, stream>>>(D1, P, 26, 512);
    ring_zero<<<(P * 100 * 32 + 255) / 256, 256, 0, stream>>>(D2, P, 26, 256);
    for (int c = 0; c < nchunks; ++c) {
        int p0 = c * P;
        // conv1: 128->512 from padded image (MODE0), MT=8/NT=3, NC=4
        mfma_conv<8, 3, 0><<<swiz_grid(P, 4, 3), 256, 0, stream>>>(
            X16i, W1h, b1, D1, 128, 512, 194, 26, P, 4, p0);
        // conv2: 512->256 (MODE1), MT=8/NT=3, NC=2
        mfma_conv<8, 3, 1><<<swiz_grid(P, 2, 3), 256, 0, stream>>>(
            D1, W2h, b2, D2, 512, 256, 26, 26, P, 2, 0);
        // score: sigmoid, px-split x3
        mfma_score<1, 1, 3><<<P * 3, 256, 0, stream>>>(
            D2, W3p, b3, score + (size_t)p0 * 576, 256, 26, P, 3);
    }
    att_finalize<<<288, 256, 0, stream>>>(score, out + 73728);

    // ---- registration path (aliases chunk region; att chain complete) ----
    {
        _Float16* A1 = ws + fixed_h;
        _Float16* A2 = A1 + ((P >= 150) ? regA_h : (size_t)194 * 194 * 512);
        if (P >= 150) {
            ring_zero<<<(2 * 772 * 64 + 255) / 256, 256, 0, stream>>>(A1, 2, 194, 512);
            ring_zero<<<(2 * 772 * 8  + 255) / 256, 256, 0, stream>>>(A2, 2, 194, 64);
            mfma_conv<8, 3, 2><<<swiz_grid(128, 4, 3), 256, 0, stream>>>(
                X16i, Wr1h, br1, A1, 128, 512, 194, 194, 128, 4, 0);
            mfma_conv<4, 3, 2><<<swiz_grid(128, 1, 3), 256, 0, stream>>>(
                A1, Wr2h, br2, A2, 512, 64, 194, 194, 128, 1, 0);
            mfma_score<2, 2, 3><<<128 * 3, 256, 0, stream>>>(
                A2, Wr3p, br3, out, 64, 194, 128, 3);
        } else {
            for (int b = 0; b < 2; ++b) {
                ring_zero<<<(772 * 64 + 255) / 256, 256, 0, stream>>>(A1, 1, 194, 512);
                ring_zero<<<(772 * 8  + 255) / 256, 256, 0, stream>>>(A2, 1, 194, 64);
                mfma_conv<8, 3, 2><<<swiz_grid(64, 4, 3), 256, 0, stream>>>(
                    X16i + (size_t)b * 194 * 194 * 128, Wr1h, br1, A1,
                    128, 512, 194, 194, 64, 4, 0);
                mfma_conv<4, 3, 2><<<swiz_grid(64, 1, 3), 256, 0, stream>>>(
                    A1, Wr2h, br2, A2, 512, 64, 194, 194, 64, 1, 0);
                mfma_score<2, 2, 3><<<64 * 3, 256, 0, stream>>>(
                    A2, Wr3p, br3, out + (size_t)b * 36864, 64, 194, 64, 3);
            }
        }
    }
}